// Round 1
// baseline (1231.024 us; speedup 1.0000x reference)
//
#include <hip/hip_runtime.h>

#define N_GRID 262144
#define BSZ 128
#define NNZ_TOT 1835008

// ws layout:
// [0, YBYTES)            : Y  (N_GRID x BSZ f32)  -- SpMV result, transposed layout
// [YBYTES, +5120)        : accumulators, doubles: s1[128], t2[128], s2[128], s3[128], s4[128]
// [YBYTES+5120, +YBYTES) : ypT (N_GRID x BSZ f32) -- y_pred transposed
#define YBYTES ((size_t)N_GRID * BSZ * 4)
#define ACC_DOUBLES (5 * BSZ)

// ---- K1: transpose y_pred (BSZ, N) -> ypT (N, BSZ) ----
__global__ __launch_bounds__(256) void transpose_kernel(const float* __restrict__ yp,
                                                        float* __restrict__ ypT) {
    __shared__ float tile[32][33];
    int n0 = blockIdx.x * 32;
    int b0 = blockIdx.y * 32;
    int tx = threadIdx.x;  // 0..31
    int ty = threadIdx.y;  // 0..7
#pragma unroll
    for (int j = 0; j < 4; ++j) {
        int b = b0 + ty + j * 8;
        tile[ty + j * 8][tx] = yp[(size_t)b * N_GRID + n0 + tx];
    }
    __syncthreads();
#pragma unroll
    for (int j = 0; j < 4; ++j) {
        int n = n0 + ty + j * 8;
        ypT[(size_t)n * BSZ + b0 + tx] = tile[tx][ty + j * 8];
    }
}

// ---- K2: per-batch s1 = <y_true, y_pred>, t2 = <y_true, y_true> ----
__global__ __launch_bounds__(256) void dot_kernel(const float* __restrict__ yp,
                                                  const float* __restrict__ yt,
                                                  double* __restrict__ s1,
                                                  double* __restrict__ t2) {
    int b = blockIdx.y;
    int chunk = N_GRID / gridDim.x;
    size_t base = (size_t)b * N_GRID + (size_t)blockIdx.x * chunk;
    double a1 = 0.0, a2 = 0.0;
    for (int i = threadIdx.x; i < chunk; i += blockDim.x) {
        float p = yp[base + i];
        float t = yt[base + i];
        a1 += (double)p * (double)t;
        a2 += (double)t * (double)t;
    }
#pragma unroll
    for (int off = 32; off; off >>= 1) {
        a1 += __shfl_down(a1, off);
        a2 += __shfl_down(a2, off);
    }
    __shared__ double l1[4], l2[4];
    int wid = threadIdx.x >> 6;
    if ((threadIdx.x & 63) == 0) { l1[wid] = a1; l2[wid] = a2; }
    __syncthreads();
    if (threadIdx.x == 0) {
        atomicAdd(&s1[b], l1[0] + l1[1] + l1[2] + l1[3]);
        atomicAdd(&t2[b], l2[0] + l2[1] + l2[2] + l2[3]);
    }
}

// ---- K3: COO scatter SpMV into Y (N, BSZ) via f32 atomics ----
__global__ __launch_bounds__(256) void scatter_kernel(const float* __restrict__ ypT,
                                                      const float* __restrict__ vals,
                                                      const int* __restrict__ rows,
                                                      const int* __restrict__ cols,
                                                      float* __restrict__ Y) {
    const int K_PER_BLOCK = 1024;
    int b = threadIdx.x & 127;
    int sub = threadIdx.x >> 7;  // 0 or 1
    int k0 = blockIdx.x * K_PER_BLOCK;
    int kend = k0 + K_PER_BLOCK;
    for (int k = k0 + sub; k < kend; k += 2) {
        int r = rows[k];
        int c = cols[k];
        float v = vals[k];
        float contrib = v * ypT[(size_t)c * BSZ + b];
        atomicAdd(&Y[(size_t)r * BSZ + b], contrib);
    }
}

// ---- K4: fused s2 = <ypT, Y>, s3 = <y_true, Y>, s4 = <Y, Y> per batch ----
__global__ __launch_bounds__(256) void reduce_kernel(const float* __restrict__ Y,
                                                     const float* __restrict__ ypT,
                                                     const float* __restrict__ yt,
                                                     double* __restrict__ s2,
                                                     double* __restrict__ s3,
                                                     double* __restrict__ s4) {
    __shared__ float ytile[64 * 129];
    __shared__ double red[3 * BSZ];
    int b = threadIdx.x & 127;
    int sub = threadIdx.x >> 7;
    double a2 = 0.0, a3 = 0.0, a4 = 0.0;
    int nbase = blockIdx.x * 256;
    for (int t = 0; t < 4; ++t) {
        int n0 = nbase + t * 64;
        __syncthreads();  // previous tile fully consumed
        for (int idx = threadIdx.x; idx < 64 * 128; idx += 256) {
            int bb = idx >> 6;   // batch row 0..127
            int j = idx & 63;    // col within tile
            ytile[j * 129 + bb] = yt[(size_t)bb * N_GRID + n0 + j];
        }
        __syncthreads();
        for (int nl = sub; nl < 64; nl += 2) {
            size_t i = (size_t)(n0 + nl) * BSZ + b;
            float y = Y[i];
            float p = ypT[i];
            float tt = ytile[nl * 129 + b];
            a2 += (double)p * (double)y;
            a3 += (double)tt * (double)y;
            a4 += (double)y * (double)y;
        }
    }
    if (sub == 1) { red[b] = a2; red[BSZ + b] = a3; red[2 * BSZ + b] = a4; }
    __syncthreads();
    if (sub == 0) {
        atomicAdd(&s2[b], a2 + red[b]);
        atomicAdd(&s3[b], a3 + red[BSZ + b]);
        atomicAdd(&s4[b], a4 + red[2 * BSZ + b]);
    }
}

// ---- K5: loss_b = t2 - 2*scale*s3 + scale^2*s4; out = mean_b ----
__global__ __launch_bounds__(128) void finalize_kernel(const double* __restrict__ acc,
                                                       float* __restrict__ out) {
    const double* s1 = acc;
    const double* t2 = acc + BSZ;
    const double* s2 = acc + 2 * BSZ;
    const double* s3 = acc + 3 * BSZ;
    const double* s4 = acc + 4 * BSZ;
    int b = threadIdx.x;
    double scale = s1[b] / s2[b];
    double loss = t2[b] - 2.0 * scale * s3[b] + scale * scale * s4[b];
#pragma unroll
    for (int off = 32; off; off >>= 1) loss += __shfl_down(loss, off);
    __shared__ double l[2];
    if ((threadIdx.x & 63) == 0) l[threadIdx.x >> 6] = loss;
    __syncthreads();
    if (threadIdx.x == 0) out[0] = (float)((l[0] + l[1]) / (double)BSZ);
}

extern "C" void kernel_launch(void* const* d_in, const int* in_sizes, int n_in,
                              void* d_out, int out_size, void* d_ws, size_t ws_size,
                              hipStream_t stream) {
    const float* y_pred = (const float*)d_in[0];
    const float* y_true = (const float*)d_in[1];
    const float* vals   = (const float*)d_in[2];
    const int*   rows   = (const int*)d_in[3];
    const int*   cols   = (const int*)d_in[4];
    float* out = (float*)d_out;

    char* ws = (char*)d_ws;
    float*  Y   = (float*)ws;
    double* acc = (double*)(ws + YBYTES);
    float*  ypT = (float*)(ws + YBYTES + ACC_DOUBLES * sizeof(double));

    // zero Y + accumulators (ws is poisoned 0xAA before every call)
    hipMemsetAsync(Y, 0, YBYTES + ACC_DOUBLES * sizeof(double), stream);

    transpose_kernel<<<dim3(N_GRID / 32, BSZ / 32), dim3(32, 8), 0, stream>>>(y_pred, ypT);
    dot_kernel<<<dim3(32, BSZ), 256, 0, stream>>>(y_pred, y_true, acc, acc + BSZ);
    scatter_kernel<<<NNZ_TOT / 1024, 256, 0, stream>>>(ypT, vals, rows, cols, Y);
    reduce_kernel<<<N_GRID / 256, 256, 0, stream>>>(Y, ypT, y_true,
                                                    acc + 2 * BSZ, acc + 3 * BSZ, acc + 4 * BSZ);
    finalize_kernel<<<1, 128, 0, stream>>>(acc, out);
}

// Round 2
// 1166.444 us; speedup vs baseline: 1.0554x; 1.0554x over previous
//
#include <hip/hip_runtime.h>

#define N_GRID 262144
#define BSZ 128
#define NNZ_TOT 1835008

// ws layout (all 8B-aligned):
//   ypT     : N*BSZ f32      = 128 MB   (y_pred transposed)
//   acc     : 5*128 doubles  = 5120 B   (s1, t2, s2, s3, s4)
//   counts  : N ints         = 1 MB
//   ptr     : N+2 ints       = 1 MB     (CSR row pointers; +1 sentinel, +1 pad)
//   cursor  : N ints         = 1 MB     (scatter cursors)
//   bsums   : 512 ints       = 2 KB
//   pairs   : NNZ int2       = 14.7 MB  (col, bitcast val) sorted by row

// ---- K1: transpose y_pred (BSZ, N) -> ypT (N, BSZ) ----
__global__ __launch_bounds__(256) void transpose_kernel(const float* __restrict__ yp,
                                                        float* __restrict__ ypT) {
    __shared__ float tile[32][33];
    int n0 = blockIdx.x * 32;
    int b0 = blockIdx.y * 32;
    int tx = threadIdx.x;  // 0..31
    int ty = threadIdx.y;  // 0..7
#pragma unroll
    for (int j = 0; j < 4; ++j) {
        int b = b0 + ty + j * 8;
        tile[ty + j * 8][tx] = yp[(size_t)b * N_GRID + n0 + tx];
    }
    __syncthreads();
#pragma unroll
    for (int j = 0; j < 4; ++j) {
        int n = n0 + ty + j * 8;
        ypT[(size_t)n * BSZ + b0 + tx] = tile[tx][ty + j * 8];
    }
}

// ---- K2: histogram of rows ----
__global__ __launch_bounds__(256) void hist_kernel(const int* __restrict__ rows,
                                                   int* __restrict__ counts) {
    int k0 = blockIdx.x * 1024 + threadIdx.x;
    int kend = blockIdx.x * 1024 + 1024;
#pragma unroll
    for (int k = k0; k < kend; k += 256) atomicAdd(&counts[rows[k]], 1);
}

// ---- K3a: per-block exclusive scan (512 elems/block) ----
__global__ __launch_bounds__(512) void scan1_kernel(const int* __restrict__ counts,
                                                    int* __restrict__ ptr,
                                                    int* __restrict__ bsums) {
    __shared__ int sdata[512];
    int i = blockIdx.x * 512 + threadIdx.x;
    int x = counts[i];
    sdata[threadIdx.x] = x;
    __syncthreads();
    for (int off = 1; off < 512; off <<= 1) {
        int v = 0;
        if ((int)threadIdx.x >= off) v = sdata[threadIdx.x - off];
        __syncthreads();
        sdata[threadIdx.x] += v;
        __syncthreads();
    }
    ptr[i] = sdata[threadIdx.x] - x;  // exclusive within block
    if (threadIdx.x == 511) bsums[blockIdx.x] = sdata[511];
}

// ---- K3b: exclusive scan of 512 block sums, in place ----
__global__ __launch_bounds__(512) void scan2_kernel(int* __restrict__ bsums,
                                                    int* __restrict__ ptr) {
    __shared__ int sdata[512];
    int x = bsums[threadIdx.x];
    sdata[threadIdx.x] = x;
    __syncthreads();
    for (int off = 1; off < 512; off <<= 1) {
        int v = 0;
        if ((int)threadIdx.x >= off) v = sdata[threadIdx.x - off];
        __syncthreads();
        sdata[threadIdx.x] += v;
        __syncthreads();
    }
    bsums[threadIdx.x] = sdata[threadIdx.x] - x;
    if (threadIdx.x == 0) ptr[N_GRID] = NNZ_TOT;
}

// ---- K3c: add block offsets, init cursors ----
__global__ __launch_bounds__(512) void scan3_kernel(int* __restrict__ ptr,
                                                    int* __restrict__ cursor,
                                                    const int* __restrict__ bsums) {
    int i = blockIdx.x * 512 + threadIdx.x;
    int v = ptr[i] + bsums[blockIdx.x];
    ptr[i] = v;
    cursor[i] = v;
}

// ---- K4: scatter (col,val) pairs into CSR order ----
__global__ __launch_bounds__(256) void csr_scatter_kernel(const float* __restrict__ vals,
                                                          const int* __restrict__ rows,
                                                          const int* __restrict__ cols,
                                                          int* __restrict__ cursor,
                                                          int2* __restrict__ pairs) {
    int k0 = blockIdx.x * 1024 + threadIdx.x;
    int kend = blockIdx.x * 1024 + 1024;
#pragma unroll
    for (int k = k0; k < kend; k += 256) {
        int r = rows[k];
        int pos = atomicAdd(&cursor[r], 1);
        pairs[pos] = make_int2(cols[k], __float_as_int(vals[k]));
    }
}

// ---- K5: fused SpMV + all five per-batch reductions ----
// Per row n, lane b: y = sum_j v_j * ypT[c_j*128+b]; fold into s2,s3,s4.
// s1,t2 come free from p=ypT[n][b] and tt=yt[n][b] (LDS-transposed tile).
__global__ __launch_bounds__(256) void fused_kernel(const float* __restrict__ ypT,
                                                    const float* __restrict__ yt,
                                                    const int* __restrict__ ptr,
                                                    const int2* __restrict__ pairs,
                                                    double* __restrict__ acc) {
    __shared__ float ytile[64 * 129];
    __shared__ double red[5 * BSZ];
    int b = threadIdx.x & 127;
    int g = threadIdx.x >> 7;  // 0 or 1
    double a1 = 0.0, at2 = 0.0, a2 = 0.0, a3 = 0.0, a4 = 0.0;
    int nbase = blockIdx.x * 128;
    for (int t = 0; t < 2; ++t) {
        int n0 = nbase + t * 64;
        __syncthreads();  // previous tile consumed
        for (int idx = threadIdx.x; idx < 64 * 128; idx += 256) {
            int bb = idx >> 6;   // batch 0..127
            int j = idx & 63;    // row-local 0..63
            ytile[j * 129 + bb] = yt[(size_t)bb * N_GRID + n0 + j];
        }
        __syncthreads();
        for (int nl = g; nl < 64; nl += 2) {
            int n = n0 + nl;
            int e0 = ptr[n];
            int e1 = ptr[n + 1];
            float y = 0.0f;
            for (int e = e0; e < e1; ++e) {
                int2 pr = pairs[e];
                y += __int_as_float(pr.y) * ypT[(size_t)pr.x * BSZ + b];
            }
            float p = ypT[(size_t)n * BSZ + b];
            float tt = ytile[nl * 129 + b];
            a1 += (double)tt * (double)p;
            at2 += (double)tt * (double)tt;
            a2 += (double)p * (double)y;
            a3 += (double)tt * (double)y;
            a4 += (double)y * (double)y;
        }
    }
    if (g == 1) {
        red[b] = a1; red[BSZ + b] = at2; red[2 * BSZ + b] = a2;
        red[3 * BSZ + b] = a3; red[4 * BSZ + b] = a4;
    }
    __syncthreads();
    if (g == 0) {
        atomicAdd(&acc[b], a1 + red[b]);
        atomicAdd(&acc[BSZ + b], at2 + red[BSZ + b]);
        atomicAdd(&acc[2 * BSZ + b], a2 + red[2 * BSZ + b]);
        atomicAdd(&acc[3 * BSZ + b], a3 + red[3 * BSZ + b]);
        atomicAdd(&acc[4 * BSZ + b], a4 + red[4 * BSZ + b]);
    }
}

// ---- K6: loss_b = t2 - 2*scale*s3 + scale^2*s4; out = mean_b ----
__global__ __launch_bounds__(128) void finalize_kernel(const double* __restrict__ acc,
                                                       float* __restrict__ out) {
    const double* s1 = acc;
    const double* t2 = acc + BSZ;
    const double* s2 = acc + 2 * BSZ;
    const double* s3 = acc + 3 * BSZ;
    const double* s4 = acc + 4 * BSZ;
    int b = threadIdx.x;
    double scale = s1[b] / s2[b];
    double loss = t2[b] - 2.0 * scale * s3[b] + scale * scale * s4[b];
#pragma unroll
    for (int off = 32; off; off >>= 1) loss += __shfl_down(loss, off);
    __shared__ double l[2];
    if ((threadIdx.x & 63) == 0) l[threadIdx.x >> 6] = loss;
    __syncthreads();
    if (threadIdx.x == 0) out[0] = (float)((l[0] + l[1]) / (double)BSZ);
}

extern "C" void kernel_launch(void* const* d_in, const int* in_sizes, int n_in,
                              void* d_out, int out_size, void* d_ws, size_t ws_size,
                              hipStream_t stream) {
    const float* y_pred = (const float*)d_in[0];
    const float* y_true = (const float*)d_in[1];
    const float* vals   = (const float*)d_in[2];
    const int*   rows   = (const int*)d_in[3];
    const int*   cols   = (const int*)d_in[4];
    float* out = (float*)d_out;

    char* ws = (char*)d_ws;
    float*  ypT    = (float*)ws;                       // 128 MB
    double* acc    = (double*)(ws + (size_t)N_GRID * BSZ * 4);
    int*    counts = (int*)((char*)acc + 5 * BSZ * 8);
    int*    ptr    = counts + N_GRID;                  // N+2 ints (1 sentinel + 1 pad)
    int*    cursor = ptr + N_GRID + 2;
    int*    bsums  = cursor + N_GRID;
    int2*   pairs  = (int2*)(bsums + 512);

    // zero acc + counts in one shot (adjacent)
    hipMemsetAsync(acc, 0, 5 * BSZ * 8 + (size_t)N_GRID * 4, stream);

    transpose_kernel<<<dim3(N_GRID / 32, BSZ / 32), dim3(32, 8), 0, stream>>>(y_pred, ypT);
    hist_kernel<<<NNZ_TOT / 1024, 256, 0, stream>>>(rows, counts);
    scan1_kernel<<<N_GRID / 512, 512, 0, stream>>>(counts, ptr, bsums);
    scan2_kernel<<<1, 512, 0, stream>>>(bsums, ptr);
    scan3_kernel<<<N_GRID / 512, 512, 0, stream>>>(ptr, cursor, bsums);
    csr_scatter_kernel<<<NNZ_TOT / 1024, 256, 0, stream>>>(vals, rows, cols, cursor, pairs);
    fused_kernel<<<N_GRID / 128, 256, 0, stream>>>(ypT, y_true, ptr, pairs, acc);
    finalize_kernel<<<1, 128, 0, stream>>>(acc, out);
}

// Round 3
// 843.376 us; speedup vs baseline: 1.4596x; 1.3831x over previous
//
#include <hip/hip_runtime.h>

#define N_GRID 262144
#define BSZ 128
#define NNZ_TOT 1835008
#define ROWS_PER_BLOCK 32
#define NBLK_FUSED (N_GRID / ROWS_PER_BLOCK)   // 8192

// ws layout (8B-aligned):
//   ypT     : N*BSZ f32        = 128 MB   (y_pred transposed)
//   acc     : 5*128 doubles    = 5120 B   (s1, t2, s2, s3, s4)
//   counts  : N ints           = 1 MB
//   ptr     : N+2 ints         = 1 MB     (CSR row pointers)
//   cursor  : N ints           = 1 MB
//   bsums   : 512 ints         = 2 KB
//   pairs   : NNZ int2         = 14.7 MB  (col, bitcast val), row-sorted
//   partial : NBLK_FUSED*640 f64 = 40 MB  (per-block partial sums)

// ---- K1: transpose y_pred (BSZ, N) -> ypT (N, BSZ) ----
__global__ __launch_bounds__(256) void transpose_kernel(const float* __restrict__ yp,
                                                        float* __restrict__ ypT) {
    __shared__ float tile[32][33];
    int n0 = blockIdx.x * 32;
    int b0 = blockIdx.y * 32;
    int tx = threadIdx.x;  // 0..31
    int ty = threadIdx.y;  // 0..7
#pragma unroll
    for (int j = 0; j < 4; ++j) {
        int b = b0 + ty + j * 8;
        tile[ty + j * 8][tx] = yp[(size_t)b * N_GRID + n0 + tx];
    }
    __syncthreads();
#pragma unroll
    for (int j = 0; j < 4; ++j) {
        int n = n0 + ty + j * 8;
        ypT[(size_t)n * BSZ + b0 + tx] = tile[tx][ty + j * 8];
    }
}

// ---- K2: histogram of rows ----
__global__ __launch_bounds__(256) void hist_kernel(const int* __restrict__ rows,
                                                   int* __restrict__ counts) {
    int k0 = blockIdx.x * 1024 + threadIdx.x;
    int kend = blockIdx.x * 1024 + 1024;
#pragma unroll
    for (int k = k0; k < kend; k += 256) atomicAdd(&counts[rows[k]], 1);
}

// ---- K3a: per-block exclusive scan (512 elems/block) ----
__global__ __launch_bounds__(512) void scan1_kernel(const int* __restrict__ counts,
                                                    int* __restrict__ ptr,
                                                    int* __restrict__ bsums) {
    __shared__ int sdata[512];
    int i = blockIdx.x * 512 + threadIdx.x;
    int x = counts[i];
    sdata[threadIdx.x] = x;
    __syncthreads();
    for (int off = 1; off < 512; off <<= 1) {
        int v = 0;
        if ((int)threadIdx.x >= off) v = sdata[threadIdx.x - off];
        __syncthreads();
        sdata[threadIdx.x] += v;
        __syncthreads();
    }
    ptr[i] = sdata[threadIdx.x] - x;
    if (threadIdx.x == 511) bsums[blockIdx.x] = sdata[511];
}

// ---- K3b: exclusive scan of 512 block sums ----
__global__ __launch_bounds__(512) void scan2_kernel(int* __restrict__ bsums,
                                                    int* __restrict__ ptr) {
    __shared__ int sdata[512];
    int x = bsums[threadIdx.x];
    sdata[threadIdx.x] = x;
    __syncthreads();
    for (int off = 1; off < 512; off <<= 1) {
        int v = 0;
        if ((int)threadIdx.x >= off) v = sdata[threadIdx.x - off];
        __syncthreads();
        sdata[threadIdx.x] += v;
        __syncthreads();
    }
    bsums[threadIdx.x] = sdata[threadIdx.x] - x;
    if (threadIdx.x == 0) ptr[N_GRID] = NNZ_TOT;
}

// ---- K3c: add block offsets, init cursors ----
__global__ __launch_bounds__(512) void scan3_kernel(int* __restrict__ ptr,
                                                    int* __restrict__ cursor,
                                                    const int* __restrict__ bsums) {
    int i = blockIdx.x * 512 + threadIdx.x;
    int v = ptr[i] + bsums[blockIdx.x];
    ptr[i] = v;
    cursor[i] = v;
}

// ---- K4: scatter (col,val) pairs into CSR order ----
__global__ __launch_bounds__(256) void csr_scatter_kernel(const float* __restrict__ vals,
                                                          const int* __restrict__ rows,
                                                          const int* __restrict__ cols,
                                                          int* __restrict__ cursor,
                                                          int2* __restrict__ pairs) {
    int k0 = blockIdx.x * 1024 + threadIdx.x;
    int kend = blockIdx.x * 1024 + 1024;
#pragma unroll
    for (int k = k0; k < kend; k += 256) {
        int r = rows[k];
        int pos = atomicAdd(&cursor[r], 1);
        pairs[pos] = make_int2(cols[k], __float_as_int(vals[k]));
    }
}

// ---- K5: fused SpMV + all five per-batch reductions, partials out ----
// Block handles ROWS_PER_BLOCK rows x all 128 batch lanes.
__global__ __launch_bounds__(256) void fused_kernel(const float* __restrict__ ypT,
                                                    const float* __restrict__ yt,
                                                    const int* __restrict__ ptr,
                                                    const int2* __restrict__ pairs,
                                                    double* __restrict__ partial) {
    __shared__ float ytile[ROWS_PER_BLOCK * 129];
    __shared__ double red[5 * BSZ];
    int b = threadIdx.x & 127;
    int g = threadIdx.x >> 7;  // 0 or 1
    int n0 = blockIdx.x * ROWS_PER_BLOCK;

    // stage y_true tile (transposed): ytile[j][bb] = yt[bb][n0+j]
    for (int idx = threadIdx.x; idx < ROWS_PER_BLOCK * 128; idx += 256) {
        int bb = idx >> 5;          // 0..127
        int j = idx & 31;           // 0..31
        ytile[j * 129 + bb] = yt[(size_t)bb * N_GRID + n0 + j];
    }
    __syncthreads();

    double a1 = 0.0, at2 = 0.0, a2 = 0.0, a3 = 0.0, a4 = 0.0;
#pragma unroll 2
    for (int nl = g; nl < ROWS_PER_BLOCK; nl += 2) {
        int n = n0 + nl;
        int e0 = ptr[n];
        int e1 = ptr[n + 1];
        float y = 0.0f;
        int e = e0;
        for (; e + 4 <= e1; e += 4) {
            int2 q0 = pairs[e];
            int2 q1 = pairs[e + 1];
            int2 q2 = pairs[e + 2];
            int2 q3 = pairs[e + 3];
            float g0 = ypT[(size_t)q0.x * BSZ + b];
            float g1 = ypT[(size_t)q1.x * BSZ + b];
            float g2 = ypT[(size_t)q2.x * BSZ + b];
            float g3 = ypT[(size_t)q3.x * BSZ + b];
            y = fmaf(__int_as_float(q0.y), g0, y);
            y = fmaf(__int_as_float(q1.y), g1, y);
            y = fmaf(__int_as_float(q2.y), g2, y);
            y = fmaf(__int_as_float(q3.y), g3, y);
        }
        for (; e < e1; ++e) {
            int2 q = pairs[e];
            y = fmaf(__int_as_float(q.y), ypT[(size_t)q.x * BSZ + b], y);
        }
        float p = ypT[(size_t)n * BSZ + b];
        float tt = ytile[nl * 129 + b];
        a1 += (double)tt * (double)p;
        at2 += (double)tt * (double)tt;
        a2 += (double)p * (double)y;
        a3 += (double)tt * (double)y;
        a4 += (double)y * (double)y;
    }

    if (g == 1) {
        red[b] = a1; red[BSZ + b] = at2; red[2 * BSZ + b] = a2;
        red[3 * BSZ + b] = a3; red[4 * BSZ + b] = a4;
    }
    __syncthreads();
    if (g == 0) {
        double* pb = partial + (size_t)blockIdx.x * (5 * BSZ);
        pb[b] = a1 + red[b];
        pb[BSZ + b] = at2 + red[BSZ + b];
        pb[2 * BSZ + b] = a2 + red[2 * BSZ + b];
        pb[3 * BSZ + b] = a3 + red[3 * BSZ + b];
        pb[4 * BSZ + b] = a4 + red[4 * BSZ + b];
    }
}

// ---- K6: reduce partials into acc (grid: (5, 16), 128 threads) ----
__global__ __launch_bounds__(128) void reduce2_kernel(const double* __restrict__ partial,
                                                      double* __restrict__ acc) {
    int s = blockIdx.x;        // 0..4
    int chunk = blockIdx.y;    // 0..15
    int b = threadIdx.x;       // 0..127
    const int PER = NBLK_FUSED / 16;  // 512
    double sum = 0.0;
    int i0 = chunk * PER;
#pragma unroll 4
    for (int i = 0; i < PER; ++i) {
        sum += partial[(size_t)(i0 + i) * (5 * BSZ) + s * BSZ + b];
    }
    atomicAdd(&acc[s * BSZ + b], sum);
}

// ---- K7: loss_b = t2 - 2*scale*s3 + scale^2*s4; out = mean_b ----
__global__ __launch_bounds__(128) void finalize_kernel(const double* __restrict__ acc,
                                                       float* __restrict__ out) {
    const double* s1 = acc;
    const double* t2 = acc + BSZ;
    const double* s2 = acc + 2 * BSZ;
    const double* s3 = acc + 3 * BSZ;
    const double* s4 = acc + 4 * BSZ;
    int b = threadIdx.x;
    double scale = s1[b] / s2[b];
    double loss = t2[b] - 2.0 * scale * s3[b] + scale * scale * s4[b];
#pragma unroll
    for (int off = 32; off; off >>= 1) loss += __shfl_down(loss, off);
    __shared__ double l[2];
    if ((threadIdx.x & 63) == 0) l[threadIdx.x >> 6] = loss;
    __syncthreads();
    if (threadIdx.x == 0) out[0] = (float)((l[0] + l[1]) / (double)BSZ);
}

extern "C" void kernel_launch(void* const* d_in, const int* in_sizes, int n_in,
                              void* d_out, int out_size, void* d_ws, size_t ws_size,
                              hipStream_t stream) {
    const float* y_pred = (const float*)d_in[0];
    const float* y_true = (const float*)d_in[1];
    const float* vals   = (const float*)d_in[2];
    const int*   rows   = (const int*)d_in[3];
    const int*   cols   = (const int*)d_in[4];
    float* out = (float*)d_out;

    char* ws = (char*)d_ws;
    float*  ypT    = (float*)ws;                       // 128 MB
    double* acc    = (double*)(ws + (size_t)N_GRID * BSZ * 4);
    int*    counts = (int*)((char*)acc + 5 * BSZ * 8);
    int*    ptr    = counts + N_GRID;
    int*    cursor = ptr + N_GRID + 2;
    int*    bsums  = cursor + N_GRID;
    int2*   pairs  = (int2*)(bsums + 512);
    double* partial = (double*)(pairs + NNZ_TOT);      // 40 MB

    // zero acc + counts (adjacent in ws)
    hipMemsetAsync(acc, 0, 5 * BSZ * 8 + (size_t)N_GRID * 4, stream);

    transpose_kernel<<<dim3(N_GRID / 32, BSZ / 32), dim3(32, 8), 0, stream>>>(y_pred, ypT);
    hist_kernel<<<NNZ_TOT / 1024, 256, 0, stream>>>(rows, counts);
    scan1_kernel<<<N_GRID / 512, 512, 0, stream>>>(counts, ptr, bsums);
    scan2_kernel<<<1, 512, 0, stream>>>(bsums, ptr);
    scan3_kernel<<<N_GRID / 512, 512, 0, stream>>>(ptr, cursor, bsums);
    csr_scatter_kernel<<<NNZ_TOT / 1024, 256, 0, stream>>>(vals, rows, cols, cursor, pairs);
    fused_kernel<<<NBLK_FUSED, 256, 0, stream>>>(ypT, y_true, ptr, pairs, partial);
    reduce2_kernel<<<dim3(5, 16), 128, 0, stream>>>(partial, acc);
    finalize_kernel<<<1, 128, 0, stream>>>(acc, out);
}

// Round 4
// 765.638 us; speedup vs baseline: 1.6078x; 1.1015x over previous
//
#include <hip/hip_runtime.h>

#define N_GRID 262144
#define BSZ 128
#define NNZ_TOT 1835008
#define ROWS_PER_BLOCK 32
#define NBLK_FUSED (N_GRID / ROWS_PER_BLOCK)   // 8192
#define PAIR_CAP (NNZ_TOT + 7 * N_GRID)        // padded-to-8 worst case = 3670016

// ws layout (8B-aligned):
//   ypT     : N*BSZ f32          = 128 MB  (y_pred transposed)
//   acc     : 5*128 doubles      = 5120 B  (s1, t2, s2, s3, s4)
//   counts  : N ints             = 1 MB
//   ptr     : N+2 ints           = 1 MB    (padded CSR row pointers)
//   cursor  : N ints             = 1 MB
//   bsums   : 512 ints           = 2 KB
//   pairs   : PAIR_CAP int2      = 29.4 MB (col, bitcast val), row-sorted, zero-padded
//   partial : NBLK_FUSED*640 f32 = 20 MB   (per-block partial sums)

// ---- K1: transpose y_pred (BSZ, N) -> ypT (N, BSZ), float4 both ways ----
__global__ __launch_bounds__(256) void transpose_kernel(const float* __restrict__ yp,
                                                        float* __restrict__ ypT) {
    __shared__ float tile[64 * 65];
    int n0 = blockIdx.x * 64;
    int b0 = blockIdx.y * 64;
    int tx = threadIdx.x & 15;   // 0..15 -> 4 floats each
    int ty = threadIdx.x >> 4;   // 0..15
#pragma unroll
    for (int jj = 0; jj < 4; ++jj) {
        int b = b0 + ty + jj * 16;
        float4 v = *(const float4*)&yp[(size_t)b * N_GRID + n0 + 4 * tx];
        tile[(4 * tx + 0) * 65 + ty + jj * 16] = v.x;
        tile[(4 * tx + 1) * 65 + ty + jj * 16] = v.y;
        tile[(4 * tx + 2) * 65 + ty + jj * 16] = v.z;
        tile[(4 * tx + 3) * 65 + ty + jj * 16] = v.w;
    }
    __syncthreads();
#pragma unroll
    for (int jj = 0; jj < 4; ++jj) {
        int nl = ty + jj * 16;
        float4 v;
        v.x = tile[nl * 65 + 4 * tx + 0];
        v.y = tile[nl * 65 + 4 * tx + 1];
        v.z = tile[nl * 65 + 4 * tx + 2];
        v.w = tile[nl * 65 + 4 * tx + 3];
        *(float4*)&ypT[(size_t)(n0 + nl) * BSZ + b0 + 4 * tx] = v;
    }
}

// ---- K2: histogram of rows ----
__global__ __launch_bounds__(256) void hist_kernel(const int* __restrict__ rows,
                                                   int* __restrict__ counts) {
    int k0 = blockIdx.x * 1024 + threadIdx.x;
    int kend = blockIdx.x * 1024 + 1024;
#pragma unroll
    for (int k = k0; k < kend; k += 256) atomicAdd(&counts[rows[k]], 1);
}

// ---- K3a: per-block exclusive scan of PADDED counts (512 elems/block) ----
__global__ __launch_bounds__(512) void scan1_kernel(const int* __restrict__ counts,
                                                    int* __restrict__ ptr,
                                                    int* __restrict__ bsums) {
    __shared__ int sdata[512];
    int i = blockIdx.x * 512 + threadIdx.x;
    int x = (counts[i] + 7) & ~7;   // pad each row to a multiple of 8
    sdata[threadIdx.x] = x;
    __syncthreads();
    for (int off = 1; off < 512; off <<= 1) {
        int v = 0;
        if ((int)threadIdx.x >= off) v = sdata[threadIdx.x - off];
        __syncthreads();
        sdata[threadIdx.x] += v;
        __syncthreads();
    }
    ptr[i] = sdata[threadIdx.x] - x;
    if (threadIdx.x == 511) bsums[blockIdx.x] = sdata[511];
}

// ---- K3b: exclusive scan of 512 block sums; grand total -> ptr[N] ----
__global__ __launch_bounds__(512) void scan2_kernel(int* __restrict__ bsums,
                                                    int* __restrict__ ptr) {
    __shared__ int sdata[512];
    int x = bsums[threadIdx.x];
    sdata[threadIdx.x] = x;
    __syncthreads();
    for (int off = 1; off < 512; off <<= 1) {
        int v = 0;
        if ((int)threadIdx.x >= off) v = sdata[threadIdx.x - off];
        __syncthreads();
        sdata[threadIdx.x] += v;
        __syncthreads();
    }
    bsums[threadIdx.x] = sdata[threadIdx.x] - x;
    if (threadIdx.x == 511) ptr[N_GRID] = sdata[511];  // total padded count
}

// ---- K3c: add block offsets, init cursors ----
__global__ __launch_bounds__(512) void scan3_kernel(int* __restrict__ ptr,
                                                    int* __restrict__ cursor,
                                                    const int* __restrict__ bsums) {
    int i = blockIdx.x * 512 + threadIdx.x;
    int v = ptr[i] + bsums[blockIdx.x];
    ptr[i] = v;
    cursor[i] = v;
}

// ---- K4: scatter (col,val) pairs into padded CSR slots ----
__global__ __launch_bounds__(256) void csr_scatter_kernel(const float* __restrict__ vals,
                                                          const int* __restrict__ rows,
                                                          const int* __restrict__ cols,
                                                          int* __restrict__ cursor,
                                                          int2* __restrict__ pairs) {
    int k0 = blockIdx.x * 1024 + threadIdx.x;
    int kend = blockIdx.x * 1024 + 1024;
#pragma unroll
    for (int k = k0; k < kend; k += 256) {
        int r = rows[k];
        int pos = atomicAdd(&cursor[r], 1);
        pairs[pos] = make_int2(cols[k], __float_as_int(vals[k]));
    }
}

// ---- K5: fused SpMV + all five per-batch reductions, f32 partials out ----
__global__ __launch_bounds__(256) void fused_kernel(const float* __restrict__ ypT,
                                                    const float* __restrict__ yt,
                                                    const int* __restrict__ ptr,
                                                    const int2* __restrict__ pairs,
                                                    float* __restrict__ partial) {
    __shared__ float ytile[ROWS_PER_BLOCK * 129];
    __shared__ double red[5 * BSZ];
    int b = threadIdx.x & 127;
    int g = threadIdx.x >> 7;  // 0 or 1
    int n0 = blockIdx.x * ROWS_PER_BLOCK;

    for (int idx = threadIdx.x; idx < ROWS_PER_BLOCK * 128; idx += 256) {
        int bb = idx >> 5;
        int j = idx & 31;
        ytile[j * 129 + bb] = yt[(size_t)bb * N_GRID + n0 + j];
    }
    __syncthreads();

    double a1 = 0.0, at2 = 0.0, a2 = 0.0, a3 = 0.0, a4 = 0.0;
    for (int nl = g; nl < ROWS_PER_BLOCK; nl += 2) {
        int n = n0 + nl;
        int e0 = __builtin_amdgcn_readfirstlane(ptr[n]);
        int e1 = __builtin_amdgcn_readfirstlane(ptr[n + 1]);
        float y = 0.0f;
        // padded: (e1 - e0) % 8 == 0; zero entries contribute 0
        for (int e = e0; e < e1; e += 8) {
            int2 q[8];
#pragma unroll
            for (int u = 0; u < 8; ++u) q[u] = pairs[e + u];
            float gv[8];
#pragma unroll
            for (int u = 0; u < 8; ++u) gv[u] = ypT[(size_t)q[u].x * BSZ + b];
#pragma unroll
            for (int u = 0; u < 8; ++u) y = fmaf(__int_as_float(q[u].y), gv[u], y);
        }
        float p = ypT[(size_t)n * BSZ + b];
        float tt = ytile[nl * 129 + b];
        a1 += (double)tt * (double)p;
        at2 += (double)tt * (double)tt;
        a2 += (double)p * (double)y;
        a3 += (double)tt * (double)y;
        a4 += (double)y * (double)y;
    }

    if (g == 1) {
        red[b] = a1; red[BSZ + b] = at2; red[2 * BSZ + b] = a2;
        red[3 * BSZ + b] = a3; red[4 * BSZ + b] = a4;
    }
    __syncthreads();
    if (g == 0) {
        float* pb = partial + (size_t)blockIdx.x * (5 * BSZ);
        pb[b] = (float)(a1 + red[b]);
        pb[BSZ + b] = (float)(at2 + red[BSZ + b]);
        pb[2 * BSZ + b] = (float)(a2 + red[2 * BSZ + b]);
        pb[3 * BSZ + b] = (float)(a3 + red[3 * BSZ + b]);
        pb[4 * BSZ + b] = (float)(a4 + red[4 * BSZ + b]);
    }
}

// ---- K6: reduce partials into acc (grid: (5, 16), 128 threads) ----
__global__ __launch_bounds__(128) void reduce2_kernel(const float* __restrict__ partial,
                                                      double* __restrict__ acc) {
    int s = blockIdx.x;
    int chunk = blockIdx.y;
    int b = threadIdx.x;
    const int PER = NBLK_FUSED / 16;  // 512
    double sum = 0.0;
    int i0 = chunk * PER;
#pragma unroll 4
    for (int i = 0; i < PER; ++i) {
        sum += (double)partial[(size_t)(i0 + i) * (5 * BSZ) + s * BSZ + b];
    }
    atomicAdd(&acc[s * BSZ + b], sum);
}

// ---- K7: loss_b = t2 - 2*scale*s3 + scale^2*s4; out = mean_b ----
__global__ __launch_bounds__(128) void finalize_kernel(const double* __restrict__ acc,
                                                       float* __restrict__ out) {
    const double* s1 = acc;
    const double* t2 = acc + BSZ;
    const double* s2 = acc + 2 * BSZ;
    const double* s3 = acc + 3 * BSZ;
    const double* s4 = acc + 4 * BSZ;
    int b = threadIdx.x;
    double scale = s1[b] / s2[b];
    double loss = t2[b] - 2.0 * scale * s3[b] + scale * scale * s4[b];
#pragma unroll
    for (int off = 32; off; off >>= 1) loss += __shfl_down(loss, off);
    __shared__ double l[2];
    if ((threadIdx.x & 63) == 0) l[threadIdx.x >> 6] = loss;
    __syncthreads();
    if (threadIdx.x == 0) out[0] = (float)((l[0] + l[1]) / (double)BSZ);
}

extern "C" void kernel_launch(void* const* d_in, const int* in_sizes, int n_in,
                              void* d_out, int out_size, void* d_ws, size_t ws_size,
                              hipStream_t stream) {
    const float* y_pred = (const float*)d_in[0];
    const float* y_true = (const float*)d_in[1];
    const float* vals   = (const float*)d_in[2];
    const int*   rows   = (const int*)d_in[3];
    const int*   cols   = (const int*)d_in[4];
    float* out = (float*)d_out;

    char* ws = (char*)d_ws;
    float*  ypT    = (float*)ws;                         // 128 MB
    double* acc    = (double*)(ws + (size_t)N_GRID * BSZ * 4);
    int*    counts = (int*)((char*)acc + 5 * BSZ * 8);
    int*    ptr    = counts + N_GRID;
    int*    cursor = ptr + N_GRID + 2;
    int*    bsums  = cursor + N_GRID;
    int2*   pairs  = (int2*)(bsums + 512);               // 29.4 MB
    float*  partial = (float*)(pairs + PAIR_CAP);        // 20 MB

    // zero acc + counts (adjacent), and the padded pairs region
    hipMemsetAsync(acc, 0, 5 * BSZ * 8 + (size_t)N_GRID * 4, stream);
    hipMemsetAsync(pairs, 0, (size_t)PAIR_CAP * 8, stream);

    transpose_kernel<<<dim3(N_GRID / 64, BSZ / 64), 256, 0, stream>>>(y_pred, ypT);
    hist_kernel<<<NNZ_TOT / 1024, 256, 0, stream>>>(rows, counts);
    scan1_kernel<<<N_GRID / 512, 512, 0, stream>>>(counts, ptr, bsums);
    scan2_kernel<<<1, 512, 0, stream>>>(bsums, ptr);
    scan3_kernel<<<N_GRID / 512, 512, 0, stream>>>(ptr, cursor, bsums);
    csr_scatter_kernel<<<NNZ_TOT / 1024, 256, 0, stream>>>(vals, rows, cols, cursor, pairs);
    fused_kernel<<<NBLK_FUSED, 256, 0, stream>>>(ypT, y_true, ptr, pairs, partial);
    reduce2_kernel<<<dim3(5, 16), 128, 0, stream>>>(partial, acc);
    finalize_kernel<<<1, 128, 0, stream>>>(acc, out);
}